// Round 7
// baseline (1496.151 us; speedup 1.0000x reference)
//
#include <hip/hip_runtime.h>
#include <math.h>

#define SEQ    2048
#define BATCH  8
#define EMB    1024
#define HEADS  8
#define PROJ   64
#define CHAINS 64            // BATCH*HEADS
#define GATES  192           // 3*PROJ

typedef float f4  __attribute__((ext_vector_type(4)));
typedef short s8v __attribute__((ext_vector_type(8)));
typedef _Float16 h2v __attribute__((ext_vector_type(2)));

#define AS1(p) ((const __attribute__((address_space(1))) void*)(p))
#define AS3(p) ((__attribute__((address_space(3))) void*)(p))

static __device__ __forceinline__ float bf2f(unsigned short u) {
    union { unsigned int i; float f; } c; c.i = ((unsigned int)u) << 16; return c.f;
}
static __device__ __forceinline__ unsigned short f2bf(float f) {
    union { float f; unsigned int i; } c; c.f = f;
    unsigned int u = c.i;
    u += 0x7fffu + ((u >> 16) & 1u);   // round-to-nearest-even
    return (unsigned short)(u >> 16);
}
// dot2: c += a.x*b.x + a.y*b.y   (f16 inputs, f32 accum)
static __device__ __forceinline__ float fdot2u(unsigned int a, unsigned int b, float c) {
    union { unsigned int u; h2v h; } ua, ub; ua.u = a; ub.u = b;
    return __builtin_amdgcn_fdot2(ua.h, ub.h, c, false);
}

// ---------------------------------------------------------------------------
// f32 [R][C] -> bf16 out [C][R]   (32x32 LDS tile, both sides coalesced)
// ---------------------------------------------------------------------------
__global__ __launch_bounds__(256)
void transpose_to_bf16(const float* __restrict__ in, unsigned short* __restrict__ out,
                       int R, int C) {
    __shared__ float tile[32][33];
    const int tx = threadIdx.x & 31, ty = threadIdx.x >> 5;
    const int c0 = blockIdx.x * 32, r0 = blockIdx.y * 32;
#pragma unroll
    for (int i = 0; i < 4; ++i)
        tile[ty + i * 8][tx] = in[(size_t)(r0 + ty + i * 8) * C + c0 + tx];
    __syncthreads();
#pragma unroll
    for (int i = 0; i < 4; ++i)
        out[(size_t)(c0 + ty + i * 8) * R + r0 + tx] = f2bf(tile[tx][ty + i * 8]);
}

__global__ void convert_bf16(const float* __restrict__ in, unsigned short* __restrict__ out, int n) {
    const int i = blockIdx.x * blockDim.x + threadIdx.x;
    if (i < n) out[i] = f2bf(in[i]);
}

__global__ void convert_f16(const float* __restrict__ in, unsigned short* __restrict__ out, int n) {
    const int i = blockIdx.x * blockDim.x + threadIdx.x;
    if (i < n) {
        union { _Float16 h; unsigned short u; } c;
        c.h = (_Float16)in[i];
        out[i] = c.u;
    }
}

// ---------------------------------------------------------------------------
// bf16 MFMA GEMM:  C[M][N] = A[M][K] * BT[N][K]^T  (+ bias[N])
// PERM: output row m -> (m&63)*SEQ + (m>>6)   (ig relayout [s][c] -> [c][s])
// ---------------------------------------------------------------------------
template <int BM, int BN, int BK, bool A_F32, typename OutT, bool BIAS, bool PERM>
__global__ __launch_bounds__((BM / 64) * (BN / 64) * 64)
void gemm_mfma(const void* __restrict__ Ap, const unsigned short* __restrict__ BT,
               OutT* __restrict__ C, const float* __restrict__ bias,
               int M, int N, int K) {
    constexpr int NWN = BN / 64;
    constexpr int NW  = (BM / 64) * NWN;
    constexpr int NT  = NW * 64;
    constexpr int KP  = BK + 8;            // padded row (bf16 elems)
    __shared__ unsigned short Al[BM * KP];
    __shared__ unsigned short Bl[BN * KP];

    const int t    = threadIdx.x, lane = t & 63, wid = t >> 6;
    const int wm   = (wid / NWN) * 64, wn = (wid % NWN) * 64;
    const int bm   = blockIdx.x * BM, bn = blockIdx.y * BN;
    const int fr   = lane & 15;
    const int fq   = lane >> 4;

    f4 acc[4][4];
#pragma unroll
    for (int m = 0; m < 4; ++m)
#pragma unroll
        for (int n = 0; n < 4; ++n) acc[m][n] = f4{0.f, 0.f, 0.f, 0.f};

    const int nkt = K / BK;
    for (int kt = 0; kt < nkt; ++kt) {
        const int k0 = kt * BK;
        __syncthreads();
        constexpr int CHA = (BM * BK / 8) / NT;
#pragma unroll
        for (int i = 0; i < CHA; ++i) {
            const int ci = t + i * NT;
            const int r = ci / (BK / 8), cc = (ci % (BK / 8)) * 8;
            if constexpr (A_F32) {
                const float* A = (const float*)Ap;
                const float4 u0 = *(const float4*)&A[(size_t)(bm + r) * K + k0 + cc];
                const float4 u1 = *(const float4*)&A[(size_t)(bm + r) * K + k0 + cc + 4];
                s8v w;
                w[0] = (short)f2bf(u0.x); w[1] = (short)f2bf(u0.y);
                w[2] = (short)f2bf(u0.z); w[3] = (short)f2bf(u0.w);
                w[4] = (short)f2bf(u1.x); w[5] = (short)f2bf(u1.y);
                w[6] = (short)f2bf(u1.z); w[7] = (short)f2bf(u1.w);
                *(s8v*)&Al[r * KP + cc] = w;
            } else {
                const unsigned short* A = (const unsigned short*)Ap;
                *(s8v*)&Al[r * KP + cc] = *(const s8v*)&A[(size_t)(bm + r) * K + k0 + cc];
            }
        }
        constexpr int CHB = (BN * BK / 8) / NT;
#pragma unroll
        for (int i = 0; i < CHB; ++i) {
            const int ci = t + i * NT;
            const int r = ci / (BK / 8), cc = (ci % (BK / 8)) * 8;
            *(s8v*)&Bl[r * KP + cc] = *(const s8v*)&BT[(size_t)(bn + r) * K + k0 + cc];
        }
        __syncthreads();
#pragma unroll
        for (int ks = 0; ks < BK / 32; ++ks) {
            s8v av[4], bv[4];
#pragma unroll
            for (int m = 0; m < 4; ++m)
                av[m] = *(const s8v*)&Al[(wm + m * 16 + fr) * KP + ks * 32 + fq * 8];
#pragma unroll
            for (int n = 0; n < 4; ++n)
                bv[n] = *(const s8v*)&Bl[(wn + n * 16 + fr) * KP + ks * 32 + fq * 8];
#pragma unroll
            for (int m = 0; m < 4; ++m)
#pragma unroll
                for (int n = 0; n < 4; ++n)
                    acc[m][n] = __builtin_amdgcn_mfma_f32_16x16x32_bf16(
                        av[m], bv[n], acc[m][n], 0, 0, 0);
        }
    }

#pragma unroll
    for (int n = 0; n < 4; ++n) {
        const int col = bn + wn + n * 16 + fr;
        const float bv = BIAS ? bias[col] : 0.f;
#pragma unroll
        for (int m = 0; m < 4; ++m) {
            const int row0 = bm + wm + m * 16 + fq * 4;
#pragma unroll
            for (int j = 0; j < 4; ++j) {
                const float val = acc[m][n][j] + bv;
                const int row = row0 + j;
                const size_t orow = PERM ? ((size_t)(row & 63) * SEQ + (row >> 6))
                                         : (size_t)row;
                if constexpr (sizeof(OutT) == 4)
                    C[orow * N + col] = val;
                else
                    C[orow * N + col] = f2bf(val);
            }
        }
    }
}

// ---------------------------------------------------------------------------
// GRU scan v7: two chains per wave, h-broadcast via DPP-pack + v_readlane
// into SGPRs (zero LDS on the recurrence path), dots via v_dot2_f32_f16 with
// the h-pair as the scalar operand. No sched_barriers: chain B's dot block is
// independent VALU work that the scheduler interleaves into chain A's
// activation/readlane latency and vice versa.
// ig staged via global_load_lds double-buffer (16 steps); vmcnt(32) at block
// end (the 12 prefetch loads are the oldest VMEM ops; ys stores not drained).
// ---------------------------------------------------------------------------
__global__ __launch_bounds__(64, 1)
void gru_scan7(const unsigned short* __restrict__ w_hh16, const float* __restrict__ b_n,
               const unsigned short* __restrict__ ig, unsigned short* __restrict__ ys) {
    const int blk = blockIdx.x;                // 0..31
    const int cA = 2 * blk, cB = 2 * blk + 1;
    const int p = threadIdx.x;                 // 0..63

    __shared__ uint4 iglA[2][384];             // 2 x 6144 B (16 steps x 384 B)
    __shared__ uint4 iglB[2][384];

    // shared cell weights: rows {p, 64+p, 128+p} as f16 pairs (96 u32)
    unsigned int wru[32], wzu[32], wnu[32];
#pragma unroll
    for (int q = 0; q < 8; ++q) {
        const uint4 a = *(const uint4*)&w_hh16[(size_t)(0 * PROJ + p) * PROJ + q * 8];
        wru[4*q+0] = a.x; wru[4*q+1] = a.y; wru[4*q+2] = a.z; wru[4*q+3] = a.w;
        const uint4 b = *(const uint4*)&w_hh16[(size_t)(1 * PROJ + p) * PROJ + q * 8];
        wzu[4*q+0] = b.x; wzu[4*q+1] = b.y; wzu[4*q+2] = b.z; wzu[4*q+3] = b.w;
        const uint4 e = *(const uint4*)&w_hh16[(size_t)(2 * PROJ + p) * PROJ + q * 8];
        wnu[4*q+0] = e.x; wnu[4*q+1] = e.y; wnu[4*q+2] = e.z; wnu[4*q+3] = e.w;
    }
    const float bn = b_n[p];
    const unsigned odd = p & 1;

    float hregA = 0.f, hregB = 0.f;
    unsigned sA[32], sB[32];                   // packed f16 h-pairs (uniform)
#pragma unroll
    for (int k = 0; k < 32; ++k) { sA[k] = 0u; sB[k] = 0u; }

    const char* gA = (const char*)(ig + (size_t)cA * SEQ * GATES);
    const char* gB = (const char*)(ig + (size_t)cB * SEQ * GATES);

    // prologue: stage steps 0..15 of both chains into buffer 0
#pragma unroll
    for (int i = 0; i < 6; ++i) {
        __builtin_amdgcn_global_load_lds(AS1(gA + i * 1024 + p * 16),
                                         AS3((char*)&iglA[0][0] + i * 1024), 16, 0, 0);
        __builtin_amdgcn_global_load_lds(AS1(gB + i * 1024 + p * 16),
                                         AS3((char*)&iglB[0][0] + i * 1024), 16, 0, 0);
    }
    asm volatile("s_waitcnt vmcnt(0)" ::: "memory");

    for (int sb = 0; sb < SEQ; sb += 16) {
        const int buf = (sb >> 4) & 1;
        {   // prefetch steps sb+16..sb+31 of both chains into the other buffer
            const int nb = (sb + 16 < SEQ) ? sb + 16 : sb;
            const char* srcA = gA + (size_t)nb * (GATES * 2);
            const char* srcB = gB + (size_t)nb * (GATES * 2);
            char* dstA = (char*)&iglA[buf ^ 1][0];
            char* dstB = (char*)&iglB[buf ^ 1][0];
#pragma unroll
            for (int i = 0; i < 6; ++i) {
                __builtin_amdgcn_global_load_lds(AS1(srcA + i * 1024 + p * 16),
                                                 AS3(dstA + i * 1024), 16, 0, 0);
                __builtin_amdgcn_global_load_lds(AS1(srcB + i * 1024 + p * 16),
                                                 AS3(dstB + i * 1024), 16, 0, 0);
            }
        }

#pragma unroll
        for (int u = 0; u < 16; ++u) {
            const int s = sb + u;
            const unsigned short* ia = (const unsigned short*)&iglA[buf][0] + u * GATES;
            const unsigned short* ib = (const unsigned short*)&iglB[buf][0] + u * GATES;
            const float igrA = bf2f(ia[p]), igzA = bf2f(ia[PROJ + p]), ignA = bf2f(ia[2 * PROJ + p]);
            const float igrB = bf2f(ib[p]), igzB = bf2f(ib[PROJ + p]), ignB = bf2f(ib[2 * PROJ + p]);

            // ================= chain A =================
            {
                float ar[4] = {0.f,0.f,0.f,0.f}, az[4] = {0.f,0.f,0.f,0.f}, an[4] = {0.f,0.f,0.f,0.f};
#pragma unroll
                for (int k = 0; k < 32; ++k) {
                    const unsigned h2 = sA[k];
                    ar[k & 3] = fdot2u(h2, wru[k], ar[k & 3]);
                    an[k & 3] = fdot2u(h2, wnu[k], an[k & 3]);
                    az[k & 3] = fdot2u(h2, wzu[k], az[k & 3]);
                }
                const float hgr = (ar[0] + ar[1]) + (ar[2] + ar[3]);
                const float hgn = (an[0] + an[1]) + (an[2] + an[3]);
                const float hgz = (az[0] + az[1]) + (az[2] + az[3]);

                const float r = __builtin_amdgcn_rcpf(1.f + __expf(-(igrA + hgr)));
                const float z = __builtin_amdgcn_rcpf(1.f + __expf(-(igzA + hgz)));
                const float y  = ignA + r * (hgn + bn);
                const float e2 = __expf(2.f * y);
                const float nn = 1.f - 2.f * __builtin_amdgcn_rcpf(1.f + e2);
                const float hnew = nn + z * (hregA - nn);
                hregA = hnew;
                ys[((size_t)s * CHAINS + cA) * PROJ + p] = f2bf(hnew);

                // repack h for next step: f16, swap lane^1 via DPP, pack pair,
                // pull 32 pair-words into SGPRs via readlane
                unsigned v;
                { union { _Float16 h; unsigned short u; } cv; cv.h = (_Float16)hnew; v = cv.u; }
                const unsigned w = (unsigned)__builtin_amdgcn_update_dpp(
                    0, (int)v, 0xB1 /*quad_perm [1,0,3,2]*/, 0xF, 0xF, true);
                const unsigned lo = odd ? w : v;
                const unsigned hi = odd ? v : w;
                const unsigned packed = lo | (hi << 16);
#pragma unroll
                for (int k = 0; k < 32; ++k)
                    sA[k] = (unsigned)__builtin_amdgcn_readlane((int)packed, 2 * k);
            }

            // ================= chain B =================
            {
                float ar[4] = {0.f,0.f,0.f,0.f}, az[4] = {0.f,0.f,0.f,0.f}, an[4] = {0.f,0.f,0.f,0.f};
#pragma unroll
                for (int k = 0; k < 32; ++k) {
                    const unsigned h2 = sB[k];
                    ar[k & 3] = fdot2u(h2, wru[k], ar[k & 3]);
                    an[k & 3] = fdot2u(h2, wnu[k], an[k & 3]);
                    az[k & 3] = fdot2u(h2, wzu[k], az[k & 3]);
                }
                const float hgr = (ar[0] + ar[1]) + (ar[2] + ar[3]);
                const float hgn = (an[0] + an[1]) + (an[2] + an[3]);
                const float hgz = (az[0] + az[1]) + (az[2] + az[3]);

                const float r = __builtin_amdgcn_rcpf(1.f + __expf(-(igrB + hgr)));
                const float z = __builtin_amdgcn_rcpf(1.f + __expf(-(igzB + hgz)));
                const float y  = ignB + r * (hgn + bn);
                const float e2 = __expf(2.f * y);
                const float nn = 1.f - 2.f * __builtin_amdgcn_rcpf(1.f + e2);
                const float hnew = nn + z * (hregB - nn);
                hregB = hnew;
                ys[((size_t)s * CHAINS + cB) * PROJ + p] = f2bf(hnew);

                unsigned v;
                { union { _Float16 h; unsigned short u; } cv; cv.h = (_Float16)hnew; v = cv.u; }
                const unsigned w = (unsigned)__builtin_amdgcn_update_dpp(
                    0, (int)v, 0xB1, 0xF, 0xF, true);
                const unsigned lo = odd ? w : v;
                const unsigned hi = odd ? v : w;
                const unsigned packed = lo | (hi << 16);
#pragma unroll
                for (int k = 0; k < 32; ++k)
                    sB[k] = (unsigned)__builtin_amdgcn_readlane((int)packed, 2 * k);
            }
        }
        // next buffer's 12 loads are the oldest VMEM ops; don't drain ys stores
        asm volatile("s_waitcnt vmcnt(32)" ::: "memory");
    }
}

// ---------------------------------------------------------------------------
extern "C" void kernel_launch(void* const* d_in, const int* in_sizes, int n_in,
                              void* d_out, int out_size, void* d_ws, size_t ws_size,
                              hipStream_t stream) {
    const float* x     = (const float*)d_in[0];  // [S,B,E]
    const float* w_in  = (const float*)d_in[1];  // [E=1024, H*P=512]
    const float* w_ih  = (const float*)d_in[2];  // [192,64]  (BT layout [N][K])
    const float* w_hh  = (const float*)d_in[3];  // [192,64]
    const float* b_ih  = (const float*)d_in[4];  // [192]
    const float* b_n   = (const float*)d_in[5];  // [64]
    const float* w_out = (const float*)d_in[6];  // [H*P=512, E=1024]
    float* out = (float*)d_out;                  // [S,B,E] f32

    char* ws = (char*)d_ws;
    const size_t xp_bytes  = (size_t)SEQ * CHAINS * PROJ * 2;      // 16,777,216
    const size_t ig_bytes  = (size_t)SEQ * CHAINS * GATES * 2;     // 50,331,648
    unsigned short* xp_bf  = (unsigned short*)(ws);
    unsigned short* ysb    = (unsigned short*)(ws);                // reuse
    unsigned short* ig     = (unsigned short*)(ws + xp_bytes);     // [c][s][g]
    unsigned short* w_inT  = (unsigned short*)(ws + xp_bytes + ig_bytes);
    unsigned short* w_outT = w_inT + (size_t)512 * 1024;
    unsigned short* w_ihb  = w_outT + (size_t)1024 * 512;
    unsigned short* w_hh16 = w_ihb + (size_t)GATES * PROJ;

    // 0) weight preprocessing
    transpose_to_bf16<<<dim3(512 / 32, 1024 / 32), 256, 0, stream>>>(w_in, w_inT, 1024, 512);
    transpose_to_bf16<<<dim3(1024 / 32, 512 / 32), 256, 0, stream>>>(w_out, w_outT, 512, 1024);
    convert_bf16<<<(GATES * PROJ + 255) / 256, 256, 0, stream>>>(w_ih, w_ihb, GATES * PROJ);
    convert_f16<<<(GATES * PROJ + 255) / 256, 256, 0, stream>>>(w_hh, w_hh16, GATES * PROJ);

    // 1) xp = x @ w_in      [16384 x 512], K=1024
    gemm_mfma<128, 128, 64, true, unsigned short, false, false>
        <<<dim3(16384 / 128, 512 / 128), 256, 0, stream>>>(
            x, w_inT, xp_bf, nullptr, 16384, 512, 1024);

    // 2) ig = xp @ w_ih^T + b_ih   [131072 x 192], K=64; output PERMUTED to [c][s][g]
    gemm_mfma<128, 64, 64, false, unsigned short, true, true>
        <<<dim3(131072 / 128, 192 / 64), 128, 0, stream>>>(
            xp_bf, w_ihb, ig, b_ih, 131072, 192, 64);

    // 3) GRU scan: 2 chains per wave, register-only recurrence (ys over xp)
    gru_scan7<<<CHAINS / 2, 64, 0, stream>>>(w_hh16, b_n, ig, ysb);

    // 4) out = ys @ w_out   [16384 x 1024], K=512
    gemm_mfma<128, 128, 64, false, float, false, false>
        <<<dim3(16384 / 128, 1024 / 128), 256, 0, stream>>>(
            ysb, w_outT, out, nullptr, 16384, 1024, 512);
}

// Round 8
// 734.471 us; speedup vs baseline: 2.0370x; 2.0370x over previous
//
#include <hip/hip_runtime.h>
#include <math.h>

#define SEQ    2048
#define BATCH  8
#define EMB    1024
#define HEADS  8
#define PROJ   64
#define CHAINS 64            // BATCH*HEADS
#define GATES  192           // 3*PROJ

// gate pre-scales folded into weights/ig/bias:
//   r,z rows: -log2(e)  (so sigmoid = rcp(1+exp2(t)))
//   n rows:   +2*log2(e) (so tanh(y) = 1 - 2*rcp(1+exp2(t)))
#define SRZ (-1.4426950408889634f)
#define SN  ( 2.8853900817779268f)

typedef float f4  __attribute__((ext_vector_type(4)));
typedef short s8v __attribute__((ext_vector_type(8)));
typedef _Float16 h2v __attribute__((ext_vector_type(2)));

static __device__ __forceinline__ float bf2f(unsigned short u) {
    union { unsigned int i; float f; } c; c.i = ((unsigned int)u) << 16; return c.f;
}
static __device__ __forceinline__ unsigned short f2bf(float f) {
    union { float f; unsigned int i; } c; c.f = f;
    unsigned int u = c.i;
    u += 0x7fffu + ((u >> 16) & 1u);   // round-to-nearest-even
    return (unsigned short)(u >> 16);
}
// dot2: c += a.x*b.x + a.y*b.y   (f16 inputs, f32 accum)
static __device__ __forceinline__ float fdot2u(unsigned int a, unsigned int b, float c) {
    union { unsigned int u; h2v h; } ua, ub; ua.u = a; ub.u = b;
    return __builtin_amdgcn_fdot2(ua.h, ub.h, c, false);
}

// ---------------------------------------------------------------------------
// f32 [R][C] -> bf16 out [C][R]   (32x32 LDS tile, both sides coalesced)
// ---------------------------------------------------------------------------
__global__ __launch_bounds__(256)
void transpose_to_bf16(const float* __restrict__ in, unsigned short* __restrict__ out,
                       int R, int C) {
    __shared__ float tile[32][33];
    const int tx = threadIdx.x & 31, ty = threadIdx.x >> 5;
    const int c0 = blockIdx.x * 32, r0 = blockIdx.y * 32;
#pragma unroll
    for (int i = 0; i < 4; ++i)
        tile[ty + i * 8][tx] = in[(size_t)(r0 + ty + i * 8) * C + c0 + tx];
    __syncthreads();
#pragma unroll
    for (int i = 0; i < 4; ++i)
        out[(size_t)(c0 + ty + i * 8) * R + r0 + tx] = f2bf(tile[tx][ty + i * 8]);
}

// w_ih [192][64] f32 -> bf16 with per-row gate scale (rows<128: SRZ, else SN)
__global__ void convert_wih_scaled(const float* __restrict__ in, unsigned short* __restrict__ out) {
    const int i = blockIdx.x * blockDim.x + threadIdx.x;
    if (i < GATES * PROJ) {
        const float s = (i < 128 * PROJ) ? SRZ : SN;
        out[i] = f2bf(in[i] * s);
    }
}

// w_hh [192][64] f32 -> f16 with per-row gate scale
__global__ void convert_whh_scaled(const float* __restrict__ in, unsigned short* __restrict__ out) {
    const int i = blockIdx.x * blockDim.x + threadIdx.x;
    if (i < GATES * PROJ) {
        const float s = (i < 128 * PROJ) ? SRZ : SN;
        union { _Float16 h; unsigned short u; } c;
        c.h = (_Float16)(in[i] * s);
        out[i] = c.u;
    }
}

// b_ih [192] -> scaled f32 copy
__global__ void scale_bias(const float* __restrict__ in, float* __restrict__ out) {
    const int i = threadIdx.x;
    if (i < GATES) out[i] = in[i] * ((i < 128) ? SRZ : SN);
}

// ---------------------------------------------------------------------------
// bf16 MFMA GEMM:  C[M][N] = A[M][K] * BT[N][K]^T  (+ bias[N])
// PERM: output row m -> (m&63)*SEQ + (m>>6)   (ig relayout [s][c] -> [c][s])
// ---------------------------------------------------------------------------
template <int BM, int BN, int BK, bool A_F32, typename OutT, bool BIAS, bool PERM>
__global__ __launch_bounds__((BM / 64) * (BN / 64) * 64)
void gemm_mfma(const void* __restrict__ Ap, const unsigned short* __restrict__ BT,
               OutT* __restrict__ C, const float* __restrict__ bias,
               int M, int N, int K) {
    constexpr int NWN = BN / 64;
    constexpr int NW  = (BM / 64) * NWN;
    constexpr int NT  = NW * 64;
    constexpr int KP  = BK + 8;            // padded row (bf16 elems)
    __shared__ unsigned short Al[BM * KP];
    __shared__ unsigned short Bl[BN * KP];

    const int t    = threadIdx.x, lane = t & 63, wid = t >> 6;
    const int wm   = (wid / NWN) * 64, wn = (wid % NWN) * 64;
    const int bm   = blockIdx.x * BM, bn = blockIdx.y * BN;
    const int fr   = lane & 15;
    const int fq   = lane >> 4;

    f4 acc[4][4];
#pragma unroll
    for (int m = 0; m < 4; ++m)
#pragma unroll
        for (int n = 0; n < 4; ++n) acc[m][n] = f4{0.f, 0.f, 0.f, 0.f};

    const int nkt = K / BK;
    for (int kt = 0; kt < nkt; ++kt) {
        const int k0 = kt * BK;
        __syncthreads();
        constexpr int CHA = (BM * BK / 8) / NT;
#pragma unroll
        for (int i = 0; i < CHA; ++i) {
            const int ci = t + i * NT;
            const int r = ci / (BK / 8), cc = (ci % (BK / 8)) * 8;
            if constexpr (A_F32) {
                const float* A = (const float*)Ap;
                const float4 u0 = *(const float4*)&A[(size_t)(bm + r) * K + k0 + cc];
                const float4 u1 = *(const float4*)&A[(size_t)(bm + r) * K + k0 + cc + 4];
                s8v w;
                w[0] = (short)f2bf(u0.x); w[1] = (short)f2bf(u0.y);
                w[2] = (short)f2bf(u0.z); w[3] = (short)f2bf(u0.w);
                w[4] = (short)f2bf(u1.x); w[5] = (short)f2bf(u1.y);
                w[6] = (short)f2bf(u1.z); w[7] = (short)f2bf(u1.w);
                *(s8v*)&Al[r * KP + cc] = w;
            } else {
                const unsigned short* A = (const unsigned short*)Ap;
                *(s8v*)&Al[r * KP + cc] = *(const s8v*)&A[(size_t)(bm + r) * K + k0 + cc];
            }
        }
        constexpr int CHB = (BN * BK / 8) / NT;
#pragma unroll
        for (int i = 0; i < CHB; ++i) {
            const int ci = t + i * NT;
            const int r = ci / (BK / 8), cc = (ci % (BK / 8)) * 8;
            *(s8v*)&Bl[r * KP + cc] = *(const s8v*)&BT[(size_t)(bn + r) * K + k0 + cc];
        }
        __syncthreads();
#pragma unroll
        for (int ks = 0; ks < BK / 32; ++ks) {
            s8v av[4], bv[4];
#pragma unroll
            for (int m = 0; m < 4; ++m)
                av[m] = *(const s8v*)&Al[(wm + m * 16 + fr) * KP + ks * 32 + fq * 8];
#pragma unroll
            for (int n = 0; n < 4; ++n)
                bv[n] = *(const s8v*)&Bl[(wn + n * 16 + fr) * KP + ks * 32 + fq * 8];
#pragma unroll
            for (int m = 0; m < 4; ++m)
#pragma unroll
                for (int n = 0; n < 4; ++n)
                    acc[m][n] = __builtin_amdgcn_mfma_f32_16x16x32_bf16(
                        av[m], bv[n], acc[m][n], 0, 0, 0);
        }
    }

#pragma unroll
    for (int n = 0; n < 4; ++n) {
        const int col = bn + wn + n * 16 + fr;
        const float bv = BIAS ? bias[col] : 0.f;
#pragma unroll
        for (int m = 0; m < 4; ++m) {
            const int row0 = bm + wm + m * 16 + fq * 4;
#pragma unroll
            for (int j = 0; j < 4; ++j) {
                const float val = acc[m][n][j] + bv;
                const int row = row0 + j;
                const size_t orow = PERM ? ((size_t)(row & 63) * SEQ + (row >> 6))
                                         : (size_t)row;
                if constexpr (sizeof(OutT) == 4)
                    C[orow * N + col] = val;
                else
                    C[orow * N + col] = f2bf(val);
            }
        }
    }
}

// ---------------------------------------------------------------------------
// GRU scan v8: one chain per wave (64 blocks), zero barriers, minimal DS.
//  - h broadcast: 1 ds_write_b16 + 8 uniform ds_read_b128 per step (only DS
//    traffic in the loop).
//  - ig: register ring, depth 4, 3 plain ushort global loads per step
//    (issued ~4 steps = ~2000 cy ahead; compiler emits counted vmcnt waits).
//  - dots BLOCKED r -> n -> z so the sigmoid(r)/tanh chain overlaps the
//    n/z-gate dot issue.
//  - gate scales pre-folded: sigmoid = rcp(1+exp2(t)), tanh-part =
//    1-2*rcp(1+exp2(t)) with t coming straight off the dot sums.
// ---------------------------------------------------------------------------
__global__ __launch_bounds__(64, 1)
void gru_scan8(const unsigned short* __restrict__ w_hh16, const float* __restrict__ b_n,
               const unsigned short* __restrict__ ig, unsigned short* __restrict__ ys) {
    const int c = blockIdx.x;   // chain
    const int p = threadIdx.x;  // output index 0..63

    __shared__ unsigned short hl16[PROJ];   // h as f16 (128 B)

    // weights rows {p, 64+p, 128+p} as f16 pairs (96 u32), pre-scaled
    unsigned int wru[32], wzu[32], wnu[32];
#pragma unroll
    for (int q = 0; q < 8; ++q) {
        const uint4 a = *(const uint4*)&w_hh16[(size_t)(0 * PROJ + p) * PROJ + q * 8];
        wru[4*q+0] = a.x; wru[4*q+1] = a.y; wru[4*q+2] = a.z; wru[4*q+3] = a.w;
        const uint4 b = *(const uint4*)&w_hh16[(size_t)(1 * PROJ + p) * PROJ + q * 8];
        wzu[4*q+0] = b.x; wzu[4*q+1] = b.y; wzu[4*q+2] = b.z; wzu[4*q+3] = b.w;
        const uint4 e = *(const uint4*)&w_hh16[(size_t)(2 * PROJ + p) * PROJ + q * 8];
        wnu[4*q+0] = e.x; wnu[4*q+1] = e.y; wnu[4*q+2] = e.z; wnu[4*q+3] = e.w;
    }
    const float bn2 = b_n[p] * SN;   // pre-scaled n-bias

    float hreg = 0.f;
    unsigned int hw[32];             // h as packed f16 pairs
#pragma unroll
    for (int k = 0; k < 32; ++k) hw[k] = 0u;

    const unsigned short* igc = ig + (size_t)c * SEQ * GATES + p;

    // depth-4 register ring of pre-scaled bf16 gate inputs
    unsigned short pr[4], pz[4], pn[4];
#pragma unroll
    for (int k = 0; k < 4; ++k) {
        const unsigned short* g = igc + (size_t)k * GATES;
        pr[k] = g[0]; pz[k] = g[PROJ]; pn[k] = g[2 * PROJ];
    }

#pragma unroll 4
    for (int s = 0; s < SEQ; ++s) {
        const int u = s & 3;
        const float tr = bf2f(pr[u]);   // -log2e * ig_r
        const float tz = bf2f(pz[u]);   // -log2e * ig_z
        const float tn = bf2f(pn[u]);   // 2log2e * ig_n
        {   // refill ring slot (consumed 4 steps later)
            int sn = s + 4; if (sn > SEQ - 1) sn = SEQ - 1;
            const unsigned short* g = igc + (size_t)sn * GATES;
            pr[u] = g[0]; pz[u] = g[PROJ]; pn[u] = g[2 * PROJ];
        }

        // ---- blocked dots: r first (its activation chain is longest) ----
        float ar[4] = {0.f, 0.f, 0.f, 0.f};
#pragma unroll
        for (int k = 0; k < 32; ++k) ar[k & 3] = fdot2u(hw[k], wru[k], ar[k & 3]);
        const float hgr = (ar[0] + ar[1]) + (ar[2] + ar[3]);

        float an[4] = {0.f, 0.f, 0.f, 0.f};
#pragma unroll
        for (int k = 0; k < 32; ++k) an[k & 3] = fdot2u(hw[k], wnu[k], an[k & 3]);
        const float hgn = (an[0] + an[1]) + (an[2] + an[3]);

        float az[4] = {0.f, 0.f, 0.f, 0.f};
#pragma unroll
        for (int k = 0; k < 32; ++k) az[k & 3] = fdot2u(hw[k], wzu[k], az[k & 3]);
        const float hgz = (az[0] + az[1]) + (az[2] + az[3]);

        // ---- activations (scales pre-folded; exp2 = v_exp_f32) ----
        const float r  = __builtin_amdgcn_rcpf(1.f + __builtin_amdgcn_exp2f(tr + hgr));
        const float z  = __builtin_amdgcn_rcpf(1.f + __builtin_amdgcn_exp2f(tz + hgz));
        const float y2 = fmaf(r, hgn + bn2, tn);                  // 2log2e * y
        const float nn = fmaf(-2.f, __builtin_amdgcn_rcpf(1.f + __builtin_amdgcn_exp2f(y2)), 1.f);
        const float hnew = nn + z * (hreg - nn);
        hreg = hnew;

        // ---- h broadcast for next step: write f16, read back 8x b128 ----
        union { _Float16 h; unsigned short u; } cv; cv.h = (_Float16)hnew;
        hl16[p] = cv.u;   // same-wave DS ordering; no barrier
#pragma unroll
        for (int q = 0; q < 8; ++q) {
            const uint4 v = ((const uint4*)hl16)[q];
            hw[4*q+0] = v.x; hw[4*q+1] = v.y; hw[4*q+2] = v.z; hw[4*q+3] = v.w;
        }
        // ys store scheduled into the LDS read latency
        ys[((size_t)s * CHAINS + c) * PROJ + p] = f2bf(hnew);
    }
}

// ---------------------------------------------------------------------------
extern "C" void kernel_launch(void* const* d_in, const int* in_sizes, int n_in,
                              void* d_out, int out_size, void* d_ws, size_t ws_size,
                              hipStream_t stream) {
    const float* x     = (const float*)d_in[0];  // [S,B,E]
    const float* w_in  = (const float*)d_in[1];  // [E=1024, H*P=512]
    const float* w_ih  = (const float*)d_in[2];  // [192,64]  (BT layout [N][K])
    const float* w_hh  = (const float*)d_in[3];  // [192,64]
    const float* b_ih  = (const float*)d_in[4];  // [192]
    const float* b_n   = (const float*)d_in[5];  // [64]
    const float* w_out = (const float*)d_in[6];  // [H*P=512, E=1024]
    float* out = (float*)d_out;                  // [S,B,E] f32

    char* ws = (char*)d_ws;
    const size_t xp_bytes  = (size_t)SEQ * CHAINS * PROJ * 2;      // 16,777,216
    const size_t ig_bytes  = (size_t)SEQ * CHAINS * GATES * 2;     // 50,331,648
    unsigned short* xp_bf  = (unsigned short*)(ws);
    unsigned short* ysb    = (unsigned short*)(ws);                // reuse
    unsigned short* ig     = (unsigned short*)(ws + xp_bytes);     // [c][s][g]
    unsigned short* w_inT  = (unsigned short*)(ws + xp_bytes + ig_bytes);
    unsigned short* w_outT = w_inT + (size_t)512 * 1024;
    unsigned short* w_ihb  = w_outT + (size_t)1024 * 512;
    unsigned short* w_hh16 = w_ihb + (size_t)GATES * PROJ;
    float*          bs     = (float*)(w_hh16 + (size_t)GATES * PROJ);  // scaled b_ih

    // 0) weight preprocessing (gate scales folded in)
    transpose_to_bf16<<<dim3(512 / 32, 1024 / 32), 256, 0, stream>>>(w_in, w_inT, 1024, 512);
    transpose_to_bf16<<<dim3(1024 / 32, 512 / 32), 256, 0, stream>>>(w_out, w_outT, 512, 1024);
    convert_wih_scaled<<<(GATES * PROJ + 255) / 256, 256, 0, stream>>>(w_ih, w_ihb);
    convert_whh_scaled<<<(GATES * PROJ + 255) / 256, 256, 0, stream>>>(w_hh, w_hh16);
    scale_bias<<<1, 256, 0, stream>>>(b_ih, bs);

    // 1) xp = x @ w_in      [16384 x 512], K=1024
    gemm_mfma<128, 128, 64, true, unsigned short, false, false>
        <<<dim3(16384 / 128, 512 / 128), 256, 0, stream>>>(
            x, w_inT, xp_bf, nullptr, 16384, 512, 1024);

    // 2) ig = xp @ w_ih^T + b_ih  (pre-scaled)  [131072 x 192], K=64; PERM to [c][s][g]
    gemm_mfma<128, 64, 64, false, unsigned short, true, true>
        <<<dim3(131072 / 128, 192 / 64), 128, 0, stream>>>(
            xp_bf, w_ihb, ig, bs, 131072, 192, 64);

    // 3) GRU scan: 1 chain per wave, 64 blocks (ys bf16 overwrites xp region)
    gru_scan8<<<CHAINS, 64, 0, stream>>>(w_hh16, b_n, ig, ysb);

    // 4) out = ys @ w_out   [16384 x 1024], K=512
    gemm_mfma<128, 128, 64, false, float, false, false>
        <<<dim3(16384 / 128, 1024 / 128), 256, 0, stream>>>(
            ysb, w_outT, out, nullptr, 16384, 1024, 512);
}